// Round 4
// baseline (6960.245 us; speedup 1.0000x reference)
//
#include <hip/hip_runtime.h>

typedef unsigned int uint;

__device__ __forceinline__ float bfl(uint u){ return __uint_as_float(u << 16); }
__device__ __forceinline__ float bfh(uint u){ return __uint_as_float(u & 0xFFFF0000u); }
__device__ __forceinline__ uint f2bfbits(float f){
    uint b = __float_as_uint(f);
    return (b + 0x7FFFu + ((b >> 16) & 1u)) >> 16;
}
__device__ __forceinline__ uint packbf2(float a, float b){
    return f2bfbits(a) | (f2bfbits(b) << 16);
}
__device__ __forceinline__ int smap(int4 m, int s){
    return (s == 0) ? m.x : (s == 1) ? m.y : (s == 2) ? m.z : m.w;
}
// nontemporal 8B load as int2 (little-endian: .x = low word)
__device__ __forceinline__ int2 ldnt(const int2* p){
    long long v = __builtin_nontemporal_load((const long long*)p);
    int2 r; r.x = (int)(v & 0xFFFFFFFFll); r.y = (int)(v >> 32); return r;
}

#define BSHIFT 7
#define BROWS 128

// ---------------- dense part ----------------

#define BM 64
#define BN 128
#define BK 32
__global__ __launch_bounds__(256) void gemm_kernel(const float* __restrict__ x,
                                                   const float* __restrict__ Wa,
                                                   const float* __restrict__ Wb,
                                                   float* __restrict__ AB, int N) {
    __shared__ float xsT[BK][BM + 4];
    __shared__ float wsm[BK][BN];
    int t = threadIdx.x;
    int rowbase = blockIdx.x * BM;
    const float* W = (blockIdx.y == 0) ? Wa : Wb;
    int nb = blockIdx.y * BN;
    int tx = t & 15, ty = t >> 4;
    float acc[4][8];
    #pragma unroll
    for (int i = 0; i < 4; i++)
        #pragma unroll
        for (int j = 0; j < 8; j++) acc[i][j] = 0.f;

    for (int k0 = 0; k0 < 256; k0 += BK) {
        {
            int r = t & 63;
            int koff = (t >> 6) * 8;
            int gr = rowbase + r; if (gr >= N) gr = N - 1;
            const float* src = x + (size_t)gr * 256 + k0 + koff;
            float4 u0 = *(const float4*)(src);
            float4 u1 = *(const float4*)(src + 4);
            xsT[koff + 0][r] = u0.x; xsT[koff + 1][r] = u0.y;
            xsT[koff + 2][r] = u0.z; xsT[koff + 3][r] = u0.w;
            xsT[koff + 4][r] = u1.x; xsT[koff + 5][r] = u1.y;
            xsT[koff + 6][r] = u1.z; xsT[koff + 7][r] = u1.w;
        }
        {
            #pragma unroll
            for (int i = 0; i < 4; i++) {
                int f = t + i * 256;
                int rr = f >> 5, c4 = f & 31;
                *(float4*)&wsm[rr][c4 * 4] =
                    *(const float4*)&W[(size_t)(k0 + rr) * 128 + c4 * 4];
            }
        }
        __syncthreads();
        #pragma unroll
        for (int kk = 0; kk < BK; ++kk) {
            float4 a  = *(const float4*)&xsT[kk][ty * 4];
            float4 b0 = *(const float4*)&wsm[kk][tx * 8];
            float4 b1 = *(const float4*)&wsm[kk][tx * 8 + 4];
            float av[4] = {a.x, a.y, a.z, a.w};
            float bv[8] = {b0.x, b0.y, b0.z, b0.w, b1.x, b1.y, b1.z, b1.w};
            #pragma unroll
            for (int i = 0; i < 4; i++)
                #pragma unroll
                for (int j = 0; j < 8; j++)
                    acc[i][j] = fmaf(av[i], bv[j], acc[i][j]);
        }
        __syncthreads();
    }
    #pragma unroll
    for (int i = 0; i < 4; i++) {
        int gr = rowbase + ty * 4 + i;
        if (gr < N) {
            float4 o0 = {acc[i][0], acc[i][1], acc[i][2], acc[i][3]};
            float4 o1 = {acc[i][4], acc[i][5], acc[i][6], acc[i][7]};
            *(float4*)&AB[(size_t)gr * 256 + nb + tx * 8]     = o0;
            *(float4*)&AB[(size_t)gr * 256 + nb + tx * 8 + 4] = o1;
        }
    }
}

// attention: Pb[n] packed bf16 [N][128]
__global__ __launch_bounds__(256) void attn_kernel(const float* __restrict__ AB,
        const float* __restrict__ w1, const float* __restrict__ b1,
        const float* __restrict__ w2, uint* __restrict__ Pb, int N) {
    __shared__ float w1s[128 * 32];
    __shared__ float b1s[32], w2s[32];
    __shared__ float aS[4][128], alS[4][128];
    int t = threadIdx.x;
    #pragma unroll
    for (int i = 0; i < 16; i++) w1s[t + i * 256] = w1[t + i * 256];
    if (t < 32) { b1s[t] = b1[t]; w2s[t] = w2[t]; }

    int w = t >> 6, lane = t & 63;
    int node = blockIdx.x * 4 + w;
    bool active = node < N;
    int nclamp = active ? node : (N - 1);
    float2 a = *(const float2*)(AB + (size_t)nclamp * 256 + lane * 2);
    float2 b = *(const float2*)(AB + (size_t)nclamp * 256 + 128 + lane * 2);
    float2 al;
    al.x = a.x + 0.5f * (a.x * a.x - a.x * b.x);
    al.y = a.y + 0.5f * (a.y * a.y - a.y * b.y);
    aS[w][lane * 2] = a.x;   aS[w][lane * 2 + 1] = a.y;
    alS[w][lane * 2] = al.x; alS[w][lane * 2 + 1] = al.y;
    __syncthreads();

    int j = lane & 31;
    const float* src = (lane < 32) ? aS[w] : alS[w];
    float acc = b1s[j];
    #pragma unroll 8
    for (int d = 0; d < 128; ++d) acc = fmaf(src[d], w1s[d * 32 + j], acc);
    float h = tanhf(acc);
    float prod = h * w2s[j];
    #pragma unroll
    for (int off = 1; off < 32; off <<= 1) prod += __shfl_xor(prod, off);
    float eo = __shfl_xor(prod, 32);
    float e0 = (lane < 32) ? prod : eo;
    float e1 = (lane < 32) ? eo : prod;
    float m = fmaxf(e0, e1);
    float p0 = expf(e0 - m), p1 = expf(e1 - m);
    float inv = 1.0f / (p0 + p1);
    float at0 = p0 * inv, at1 = p1 * inv;
    if (active) {
        float px = at0 * a.x + at1 * al.x;
        float py = at0 * a.y + at1 * al.y;
        Pb[(size_t)node * 64 + lane] = packbf2(px, py);
    }
}

// ---------------- batched CSR build ----------------

__global__ void hist_kernel(const int* __restrict__ rows, int4 map,
                            int* __restrict__ cnt, int N, int E) {
    int e = blockIdx.x * 256 + threadIdx.x;
    int s = blockIdx.y;
    if (e >= E) return;
    int r = rows[(size_t)smap(map, s) * E + e];
    atomicAdd(&cnt[s * N + r], 1);
}

__global__ __launch_bounds__(256) void scan_sums(const int* __restrict__ cnt,
        int* __restrict__ bsum, int N, int NB) {
    __shared__ int wsum[4];
    int s = blockIdx.y, bx = blockIdx.x, t = threadIdx.x;
    int base = bx * 4096 + t * 16;
    const int* c = cnt + (size_t)s * N;
    int ls = 0;
    #pragma unroll
    for (int k = 0; k < 16; k++) { int idx = base + k; if (idx < N) ls += c[idx]; }
    #pragma unroll
    for (int off = 32; off >= 1; off >>= 1) ls += __shfl_xor(ls, off);
    if ((t & 63) == 0) wsum[t >> 6] = ls;
    __syncthreads();
    if (t == 0) bsum[s * NB + bx] = wsum[0] + wsum[1] + wsum[2] + wsum[3];
}

__global__ __launch_bounds__(256) void scan_offs(const int* __restrict__ bsum,
        int* __restrict__ boff, int* __restrict__ rp, int NB, int N, int nsup) {
    int t = threadIdx.x;
    if (t < nsup) {
        int run = 0;
        for (int b = 0; b < NB; b++) {
            boff[t * NB + b] = run;
            run += bsum[t * NB + b];
        }
        rp[(size_t)t * (N + 1) + N] = run;
    }
}

__global__ __launch_bounds__(256) void scan_write(int* __restrict__ cnt,
        const int* __restrict__ boff, int* __restrict__ rp, int N, int NB) {
    __shared__ int wsum[4];
    int s = blockIdx.y, bx = blockIdx.x, t = threadIdx.x;
    int lane = t & 63, wid = t >> 6;
    int base = bx * 4096 + t * 16;
    const int* c = cnt + (size_t)s * N;
    int* rps = rp + (size_t)s * (N + 1);
    int v[16]; int ls = 0;
    #pragma unroll
    for (int k = 0; k < 16; k++) {
        int idx = base + k;
        v[k] = (idx < N) ? c[idx] : 0;
        ls += v[k];
    }
    int incl = ls;
    #pragma unroll
    for (int off = 1; off < 64; off <<= 1) {
        int y = __shfl_up(incl, off);
        if (lane >= off) incl += y;
    }
    if (lane == 63) wsum[wid] = incl;
    __syncthreads();
    int wbase = 0;
    #pragma unroll
    for (int w = 0; w < 4; w++) if (w < wid) wbase += wsum[w];
    int start = boff[s * NB + bx] + wbase + incl - ls;
    #pragma unroll
    for (int k = 0; k < 16; k++) {
        int idx = base + k;
        if (idx < N) rps[idx] = start;
        start += v[k];
    }
}

// bucket cursors: bcur[s][b] = rp[s][min(b*BROWS, N)]
__global__ void bcur_init(const int* __restrict__ rp, int* __restrict__ bcur,
                          int N, int NBK, int nsup) {
    int i = blockIdx.x * 256 + threadIdx.x;
    if (i >= NBK * nsup) return;
    int s = i / NBK, b = i - s * NBK;
    int r = b * BROWS; if (r > N) r = N;
    bcur[i] = rp[(size_t)s * (N + 1) + r];
}

// pass A: partition edges into row-buckets (write window ~NBK lines -> L2-coalesced)
__global__ __launch_bounds__(256) void fillA_kernel(const int* __restrict__ rows,
        const int* __restrict__ cols, const float* __restrict__ vals, int4 map,
        int* __restrict__ bcur, int2* __restrict__ stage, int NBK, int E) {
    int e = blockIdx.x * 256 + threadIdx.x;
    int s = blockIdx.y;
    if (e >= E) return;
    size_t off = (size_t)smap(map, s) * E + e;
    int r = rows[off];
    int b = r >> BSHIFT;
    int pos = atomicAdd(&bcur[s * NBK + b], 1);
    // pack local row (7 bits) above the 20-bit col field
    uint cw = (uint)cols[off] | ((uint)(r & (BROWS - 1)) << 20);
    stage[(size_t)s * E + pos] = make_int2((int)cw, __float_as_int(vals[off]));
}

// pass B: within-bucket counting sort into final CSR (writes land in ~32KB window)
__global__ __launch_bounds__(256) void fillB_kernel(const int2* __restrict__ stage,
        const int* __restrict__ rp, int2* __restrict__ pk, int N, int E) {
    __shared__ int lcur[BROWS];
    int s = blockIdx.y, b = blockIdx.x, t = threadIdx.x;
    const int* rps = rp + (size_t)s * (N + 1);
    int rowbase = b * BROWS;
    int nrows = N - rowbase; if (nrows > BROWS) nrows = BROWS;
    if (t < nrows) lcur[t] = rps[rowbase + t];
    __syncthreads();
    int start = rps[rowbase];
    int end = rps[rowbase + nrows];
    const int2* st = stage + (size_t)s * E;
    int2* pks = pk + (size_t)s * E;
    for (int idx = start + t; idx < end; idx += 256) {
        int2 u = ldnt(&st[idx]);
        int lr = ((uint)u.x) >> 20;
        int pos = atomicAdd(&lcur[lr], 1);
        pks[pos] = make_int2(u.x & 0xFFFFF, u.y);
    }
}

// ---------------- fused SpMM kernels ----------------

__global__ __launch_bounds__(256) void spmm_bp2(const int* __restrict__ rpA,
        const int2* __restrict__ pkA, const int* __restrict__ rpB,
        const int2* __restrict__ pkB, const uint* __restrict__ Xb,
        uint* __restrict__ outb, int N) {
    int gt = blockIdx.x * 256 + threadIdx.x;
    int row = gt >> 6, lane = gt & 63;
    if (row >= N) return;
    float sax = 0.f, say = 0.f, qax = 0.f, qay = 0.f;
    float sbx = 0.f, sby = 0.f, qbx = 0.f, qby = 0.f;
    {
        int e = rpA[row], end = rpA[row + 1];
        for (; e + 2 <= end; e += 2) {
            int2 c0 = ldnt(&pkA[e]); int2 c1 = ldnt(&pkA[e + 1]);
            uint u0 = Xb[(c0.x << 6) + lane];
            uint u1 = Xb[(c1.x << 6) + lane];
            float v0 = __int_as_float(c0.y), v1 = __int_as_float(c1.y);
            float x0 = bfl(u0), y0 = bfh(u0), x1 = bfl(u1), y1 = bfh(u1);
            sax = fmaf(v0, x0, sax); say = fmaf(v0, y0, say);
            qax = fmaf(v0 * x0, x0, qax); qay = fmaf(v0 * y0, y0, qay);
            sax = fmaf(v1, x1, sax); say = fmaf(v1, y1, say);
            qax = fmaf(v1 * x1, x1, qax); qay = fmaf(v1 * y1, y1, qay);
        }
        if (e < end) {
            int2 c0 = ldnt(&pkA[e]);
            uint u0 = Xb[(c0.x << 6) + lane];
            float v0 = __int_as_float(c0.y);
            float x0 = bfl(u0), y0 = bfh(u0);
            sax = fmaf(v0, x0, sax); say = fmaf(v0, y0, say);
            qax = fmaf(v0 * x0, x0, qax); qay = fmaf(v0 * y0, y0, qay);
        }
    }
    {
        int e = rpB[row], end = rpB[row + 1];
        for (; e + 2 <= end; e += 2) {
            int2 c0 = ldnt(&pkB[e]); int2 c1 = ldnt(&pkB[e + 1]);
            uint u0 = Xb[(c0.x << 6) + lane];
            uint u1 = Xb[(c1.x << 6) + lane];
            float v0 = __int_as_float(c0.y), v1 = __int_as_float(c1.y);
            float x0 = bfl(u0), y0 = bfh(u0), x1 = bfl(u1), y1 = bfh(u1);
            sbx = fmaf(v0, x0, sbx); sby = fmaf(v0, y0, sby);
            qbx = fmaf(v0 * x0, x0, qbx); qby = fmaf(v0 * y0, y0, qby);
            sbx = fmaf(v1, x1, sbx); sby = fmaf(v1, y1, sby);
            qbx = fmaf(v1 * x1, x1, qbx); qby = fmaf(v1 * y1, y1, qby);
        }
        if (e < end) {
            int2 c0 = ldnt(&pkB[e]);
            uint u0 = Xb[(c0.x << 6) + lane];
            float v0 = __int_as_float(c0.y);
            float x0 = bfl(u0), y0 = bfh(u0);
            sbx = fmaf(v0, x0, sbx); sby = fmaf(v0, y0, sby);
            qbx = fmaf(v0 * x0, x0, qbx); qby = fmaf(v0 * y0, y0, qby);
        }
    }
    float tx = 0.5f * ((sax * sax - qax) - (sbx * sbx - qbx));
    float ty = 0.5f * ((say * say - qay) - (sby * sby - qby));
    outb[((size_t)row << 6) + lane] = packbf2(tx, ty);
}

__global__ __launch_bounds__(256) void spmm_out(const int* __restrict__ rp0,
        const int2* __restrict__ pk0, const int* __restrict__ rp5,
        const int2* __restrict__ pk5, const int* __restrict__ rp6,
        const int2* __restrict__ pk6, const uint* __restrict__ Pb,
        const uint* __restrict__ t1b, const uint* __restrict__ t2b,
        float* __restrict__ out, int N) {
    int gt = blockIdx.x * 256 + threadIdx.x;
    int row = gt >> 6, lane = gt & 63;
    if (row >= N) return;
    float a0x = 0.f, a0y = 0.f, a5x = 0.f, a5y = 0.f, a6x = 0.f, a6y = 0.f;
    {
        int e = rp0[row], end = rp0[row + 1];
        for (; e + 2 <= end; e += 2) {
            int2 c0 = ldnt(&pk0[e]); int2 c1 = ldnt(&pk0[e + 1]);
            uint u0 = Pb[(c0.x << 6) + lane];
            uint u1 = Pb[(c1.x << 6) + lane];
            float v0 = __int_as_float(c0.y), v1 = __int_as_float(c1.y);
            a0x = fmaf(v0, bfl(u0), a0x); a0y = fmaf(v0, bfh(u0), a0y);
            a0x = fmaf(v1, bfl(u1), a0x); a0y = fmaf(v1, bfh(u1), a0y);
        }
        if (e < end) {
            int2 c0 = ldnt(&pk0[e]);
            uint u0 = Pb[(c0.x << 6) + lane];
            float v0 = __int_as_float(c0.y);
            a0x = fmaf(v0, bfl(u0), a0x); a0y = fmaf(v0, bfh(u0), a0y);
        }
    }
    {
        int e = rp5[row], end = rp5[row + 1];
        for (; e + 2 <= end; e += 2) {
            int2 c0 = ldnt(&pk5[e]); int2 c1 = ldnt(&pk5[e + 1]);
            uint u0 = t1b[(c0.x << 6) + lane];
            uint u1 = t1b[(c1.x << 6) + lane];
            float v0 = __int_as_float(c0.y), v1 = __int_as_float(c1.y);
            a5x = fmaf(v0, bfl(u0), a5x); a5y = fmaf(v0, bfh(u0), a5y);
            a5x = fmaf(v1, bfl(u1), a5x); a5y = fmaf(v1, bfh(u1), a5y);
        }
        if (e < end) {
            int2 c0 = ldnt(&pk5[e]);
            uint u0 = t1b[(c0.x << 6) + lane];
            float v0 = __int_as_float(c0.y);
            a5x = fmaf(v0, bfl(u0), a5x); a5y = fmaf(v0, bfh(u0), a5y);
        }
    }
    {
        int e = rp6[row], end = rp6[row + 1];
        for (; e + 2 <= end; e += 2) {
            int2 c0 = ldnt(&pk6[e]); int2 c1 = ldnt(&pk6[e + 1]);
            uint u0 = t2b[(c0.x << 6) + lane];
            uint u1 = t2b[(c1.x << 6) + lane];
            float v0 = __int_as_float(c0.y), v1 = __int_as_float(c1.y);
            a6x = fmaf(v0, bfl(u0), a6x); a6y = fmaf(v0, bfh(u0), a6y);
            a6x = fmaf(v1, bfl(u1), a6x); a6y = fmaf(v1, bfh(u1), a6y);
        }
        if (e < end) {
            int2 c0 = ldnt(&pk6[e]);
            uint u0 = t2b[(c0.x << 6) + lane];
            float v0 = __int_as_float(c0.y);
            a6x = fmaf(v0, bfl(u0), a6x); a6y = fmaf(v0, bfh(u0), a6y);
        }
    }
    float rx = fmaxf(0.5f * a0x + 0.25f * a5x + 0.25f * a6x, 0.f);
    float ry = fmaxf(0.5f * a0y + 0.25f * a5y + 0.25f * a6y, 0.f);
    *(float2*)(out + ((size_t)row << 7) + (lane << 1)) = make_float2(rx, ry);
}

// ---------------- launch ----------------

extern "C" void kernel_launch(void* const* d_in, const int* in_sizes, int n_in,
                              void* d_out, int out_size, void* d_ws, size_t ws_size,
                              hipStream_t stream) {
    (void)n_in; (void)out_size; (void)ws_size;
    const float* x   = (const float*)d_in[0];
    const float* Wa  = (const float*)d_in[1];
    const float* Wb  = (const float*)d_in[2];
    const float* w1  = (const float*)d_in[4];
    const float* b1  = (const float*)d_in[5];
    const float* w2  = (const float*)d_in[6];
    const int* rows  = (const int*)d_in[7];
    const int* cols  = (const int*)d_in[8];
    const float* vals = (const float*)d_in[9];
    float* out = (float*)d_out;

    const int N = in_sizes[0] / 256;
    const int E = in_sizes[7] / 7;
    const int NB = (N + 4095) / 4096;
    const int NBK = (N + BROWS - 1) / BROWS;

    // layout: Pb|t1b|t2b (bf16 packed) | pk (4E int2) | region{stage 4E int2 / AB N*256 f32} | ints
    uint* Pb  = (uint*)d_ws;
    uint* t1b = Pb + (size_t)N * 64;
    uint* t2b = t1b + (size_t)N * 64;
    int2* pk  = (int2*)(t2b + (size_t)N * 64);
    size_t regionFloats = (size_t)N * 256;
    if ((size_t)8 * E > regionFloats) regionFloats = (size_t)8 * E;  // int2*4E = 8E floats
    int2* stage = pk + (size_t)4 * E;
    float* AB   = (float*)stage;
    int* rp   = (int*)((float*)stage + regionFloats);
    int* cur  = rp + 4 * (size_t)(N + 1);
    int* bsum = cur + 4 * (size_t)N;
    int* boff = bsum + 4 * NB;
    int* bcur = boff + 4 * NB;

    dim3 b256(256);
    int egrid = (E + 255) / 256;
    int sgrid = (N + 3) / 4;

    dim3 ggrid((N + BM - 1) / BM, 2);
    gemm_kernel<<<ggrid, b256, 0, stream>>>(x, Wa, Wb, AB, N);
    attn_kernel<<<sgrid, b256, 0, stream>>>(AB, w1, b1, w2, Pb, N);

    auto build = [&](int4 map, int nsup) {
        hipMemsetAsync(cur, 0, (size_t)nsup * N * sizeof(int), stream);
        hist_kernel<<<dim3(egrid, nsup), b256, 0, stream>>>(rows, map, cur, N, E);
        scan_sums<<<dim3(NB, nsup), b256, 0, stream>>>(cur, bsum, N, NB);
        scan_offs<<<1, b256, 0, stream>>>(bsum, boff, rp, NB, N, nsup);
        scan_write<<<dim3(NB, nsup), b256, 0, stream>>>(cur, boff, rp, N, NB);
        bcur_init<<<(NBK * nsup + 255) / 256, b256, 0, stream>>>(rp, bcur, N, NBK, nsup);
        fillA_kernel<<<dim3(egrid, nsup), b256, 0, stream>>>(rows, cols, vals, map, bcur, stage, NBK, E);
        fillB_kernel<<<dim3(NBK, nsup), b256, 0, stream>>>(stage, rp, pk, N, E);
    };

    const int NP1 = N + 1;

    // group A: slots {1,3,2,4}
    build(make_int4(1, 3, 2, 4), 4);
    spmm_bp2<<<sgrid, b256, 0, stream>>>(rp + 0 * NP1, pk + 0 * (size_t)E,
                                         rp + 1 * NP1, pk + 1 * (size_t)E, Pb, t1b, N);
    spmm_bp2<<<sgrid, b256, 0, stream>>>(rp + 2 * NP1, pk + 2 * (size_t)E,
                                         rp + 3 * NP1, pk + 3 * (size_t)E, Pb, t2b, N);

    // group B: slots {0,5,6}
    build(make_int4(0, 5, 6, 6), 3);
    spmm_out<<<sgrid, b256, 0, stream>>>(rp + 0 * NP1, pk + 0 * (size_t)E,
                                         rp + 1 * NP1, pk + 1 * (size_t)E,
                                         rp + 2 * NP1, pk + 2 * (size_t)E,
                                         Pb, t1b, t2b, out, N);
}

// Round 5
// 2816.900 us; speedup vs baseline: 2.4709x; 2.4709x over previous
//
#include <hip/hip_runtime.h>

typedef unsigned int uint;

__device__ __forceinline__ float bfl(uint u){ return __uint_as_float(u << 16); }
__device__ __forceinline__ float bfh(uint u){ return __uint_as_float(u & 0xFFFF0000u); }
__device__ __forceinline__ uint f2bfbits(float f){
    uint b = __float_as_uint(f);
    return (b + 0x7FFFu + ((b >> 16) & 1u)) >> 16;
}
__device__ __forceinline__ uint packbf2(float a, float b){
    return f2bfbits(a) | (f2bfbits(b) << 16);
}
__device__ __forceinline__ int smap(int4 m, int s){
    return (s == 0) ? m.x : (s == 1) ? m.y : (s == 2) ? m.z : m.w;
}
__device__ __forceinline__ int2 ldnt(const int2* p){
    long long v = __builtin_nontemporal_load((const long long*)p);
    int2 r; r.x = (int)(v & 0xFFFFFFFFll); r.y = (int)(v >> 32); return r;
}

#define CH 6144          // edges per chunk (LDS-staged)
#define SBSHIFT 10       // super-bucket = 1024 rows
#define SBROWS 1024

// ---------------- dense part ----------------

#define BM 64
#define BN 128
#define BK 32
__global__ __launch_bounds__(256) void gemm_kernel(const float* __restrict__ x,
                                                   const float* __restrict__ Wa,
                                                   const float* __restrict__ Wb,
                                                   float* __restrict__ AB, int N) {
    __shared__ float xsT[BK][BM + 4];
    __shared__ float wsm[BK][BN];
    int t = threadIdx.x;
    int rowbase = blockIdx.x * BM;
    const float* W = (blockIdx.y == 0) ? Wa : Wb;
    int nb = blockIdx.y * BN;
    int tx = t & 15, ty = t >> 4;
    float acc[4][8];
    #pragma unroll
    for (int i = 0; i < 4; i++)
        #pragma unroll
        for (int j = 0; j < 8; j++) acc[i][j] = 0.f;

    for (int k0 = 0; k0 < 256; k0 += BK) {
        {
            int r = t & 63;
            int koff = (t >> 6) * 8;
            int gr = rowbase + r; if (gr >= N) gr = N - 1;
            const float* src = x + (size_t)gr * 256 + k0 + koff;
            float4 u0 = *(const float4*)(src);
            float4 u1 = *(const float4*)(src + 4);
            xsT[koff + 0][r] = u0.x; xsT[koff + 1][r] = u0.y;
            xsT[koff + 2][r] = u0.z; xsT[koff + 3][r] = u0.w;
            xsT[koff + 4][r] = u1.x; xsT[koff + 5][r] = u1.y;
            xsT[koff + 6][r] = u1.z; xsT[koff + 7][r] = u1.w;
        }
        {
            #pragma unroll
            for (int i = 0; i < 4; i++) {
                int f = t + i * 256;
                int rr = f >> 5, c4 = f & 31;
                *(float4*)&wsm[rr][c4 * 4] =
                    *(const float4*)&W[(size_t)(k0 + rr) * 128 + c4 * 4];
            }
        }
        __syncthreads();
        #pragma unroll
        for (int kk = 0; kk < BK; ++kk) {
            float4 a  = *(const float4*)&xsT[kk][ty * 4];
            float4 b0 = *(const float4*)&wsm[kk][tx * 8];
            float4 b1 = *(const float4*)&wsm[kk][tx * 8 + 4];
            float av[4] = {a.x, a.y, a.z, a.w};
            float bv[8] = {b0.x, b0.y, b0.z, b0.w, b1.x, b1.y, b1.z, b1.w};
            #pragma unroll
            for (int i = 0; i < 4; i++)
                #pragma unroll
                for (int j = 0; j < 8; j++)
                    acc[i][j] = fmaf(av[i], bv[j], acc[i][j]);
        }
        __syncthreads();
    }
    #pragma unroll
    for (int i = 0; i < 4; i++) {
        int gr = rowbase + ty * 4 + i;
        if (gr < N) {
            float4 o0 = {acc[i][0], acc[i][1], acc[i][2], acc[i][3]};
            float4 o1 = {acc[i][4], acc[i][5], acc[i][6], acc[i][7]};
            *(float4*)&AB[(size_t)gr * 256 + nb + tx * 8]     = o0;
            *(float4*)&AB[(size_t)gr * 256 + nb + tx * 8 + 4] = o1;
        }
    }
}

// attention: Pb[n] packed bf16 [N][128]
__global__ __launch_bounds__(256) void attn_kernel(const float* __restrict__ AB,
        const float* __restrict__ w1, const float* __restrict__ b1,
        const float* __restrict__ w2, uint* __restrict__ Pb, int N) {
    __shared__ float w1s[128 * 32];
    __shared__ float b1s[32], w2s[32];
    __shared__ float aS[4][128], alS[4][128];
    int t = threadIdx.x;
    #pragma unroll
    for (int i = 0; i < 16; i++) w1s[t + i * 256] = w1[t + i * 256];
    if (t < 32) { b1s[t] = b1[t]; w2s[t] = w2[t]; }

    int w = t >> 6, lane = t & 63;
    int node = blockIdx.x * 4 + w;
    bool active = node < N;
    int nclamp = active ? node : (N - 1);
    float2 a = *(const float2*)(AB + (size_t)nclamp * 256 + lane * 2);
    float2 b = *(const float2*)(AB + (size_t)nclamp * 256 + 128 + lane * 2);
    float2 al;
    al.x = a.x + 0.5f * (a.x * a.x - a.x * b.x);
    al.y = a.y + 0.5f * (a.y * a.y - a.y * b.y);
    aS[w][lane * 2] = a.x;   aS[w][lane * 2 + 1] = a.y;
    alS[w][lane * 2] = al.x; alS[w][lane * 2 + 1] = al.y;
    __syncthreads();

    int j = lane & 31;
    const float* src = (lane < 32) ? aS[w] : alS[w];
    float acc = b1s[j];
    #pragma unroll 8
    for (int d = 0; d < 128; ++d) acc = fmaf(src[d], w1s[d * 32 + j], acc);
    float h = tanhf(acc);
    float prod = h * w2s[j];
    #pragma unroll
    for (int off = 1; off < 32; off <<= 1) prod += __shfl_xor(prod, off);
    float eo = __shfl_xor(prod, 32);
    float e0 = (lane < 32) ? prod : eo;
    float e1 = (lane < 32) ? eo : prod;
    float m = fmaxf(e0, e1);
    float p0 = expf(e0 - m), p1 = expf(e1 - m);
    float inv = 1.0f / (p0 + p1);
    float at0 = p0 * inv, at1 = p1 * inv;
    if (active) {
        float px = at0 * a.x + at1 * al.x;
        float py = at0 * a.y + at1 * al.y;
        Pb[(size_t)node * 64 + lane] = packbf2(px, py);
    }
}

// ---------------- CSR build: chunk-local binning, zero global atomics ----------------

// pass A: each block sorts its CH-edge chunk into super-buckets inside LDS,
// then writes the chunk's stage window LINEARLY (coalesced, amplification 1).
__global__ __launch_bounds__(256) void fill_chunk(const int* __restrict__ rows,
        const int* __restrict__ cols, const float* __restrict__ vals, int4 map,
        int2* __restrict__ stage, int* __restrict__ offTab, int* __restrict__ lenTab,
        int NSB, int nchunks, int E) {
    __shared__ int2 sbuf[CH];
    __shared__ int hist[128];
    __shared__ int wtot;
    int c = blockIdx.x, s = blockIdx.y, t = threadIdx.x;
    size_t sb = (size_t)smap(map, s) * E;
    int e0 = c * CH;
    int e1 = e0 + CH; if (e1 > E) e1 = E;
    int csz = e1 - e0;
    if (t < 128) hist[t] = 0;
    __syncthreads();
    for (int e = e0 + t; e < e1; e += 256)
        atomicAdd(&hist[(uint)rows[sb + e] >> SBSHIFT], 1);
    __syncthreads();
    int v = 0, incl = 0;
    if (t < 128) {
        v = hist[t]; incl = v;
        #pragma unroll
        for (int off = 1; off < 64; off <<= 1) {
            int y = __shfl_up(incl, off);
            if ((t & 63) >= off) incl += y;
        }
        if (t == 63) wtot = incl;
    }
    __syncthreads();
    if (t < 128) {
        int excl = incl - v + ((t >= 64) ? wtot : 0);
        hist[t] = excl;
        if (t < NSB) {
            size_t tb = ((size_t)s * nchunks + c) * NSB + t;
            offTab[tb] = excl;
            lenTab[tb] = v;
        }
    }
    __syncthreads();
    for (int e = e0 + t; e < e1; e += 256) {
        int r = rows[sb + e];
        int pos = atomicAdd(&hist[(uint)r >> SBSHIFT], 1);
        uint cw = (uint)cols[sb + e] | ((uint)(r & (SBROWS - 1)) << 20);
        sbuf[pos] = make_int2((int)cw, __float_as_int(vals[sb + e]));
    }
    __syncthreads();
    int2* dst = stage + (size_t)s * E + e0;
    for (int i = t; i < csz; i += 256) dst[i] = sbuf[i];
}

// bucket totals + exclusive scan -> bucket base offsets (one block per support)
__global__ __launch_bounds__(256) void bucket_scan(const int* __restrict__ lenTab,
        int* __restrict__ bbase, int NSB, int nchunks) {
    __shared__ int tot[128];
    __shared__ int wtot;
    int s = blockIdx.x, t = threadIdx.x;
    if (t < 128) tot[t] = 0;
    __syncthreads();
    if (t < NSB) {
        int acc = 0;
        for (int c = 0; c < nchunks; ++c)
            acc += lenTab[((size_t)s * nchunks + c) * NSB + t];
        tot[t] = acc;
    }
    __syncthreads();
    int v = 0, incl = 0;
    if (t < 128) {
        v = tot[t]; incl = v;
        #pragma unroll
        for (int off = 1; off < 64; off <<= 1) {
            int y = __shfl_up(incl, off);
            if ((t & 63) >= off) incl += y;
        }
        if (t == 63) wtot = incl;
    }
    __syncthreads();
    if (t < NSB) bbase[s * NSB + t] = incl - v + ((t >= 64) ? wtot : 0);
}

__device__ __forceinline__ void block_scan1024(int* a, int t, int* wsum) {
    int lane = t & 63, wid = t >> 6;
    int c0 = a[t * 4], c1 = a[t * 4 + 1], c2 = a[t * 4 + 2], c3 = a[t * 4 + 3];
    int tsum = c0 + c1 + c2 + c3, incl = tsum;
    #pragma unroll
    for (int off = 1; off < 64; off <<= 1) {
        int y = __shfl_up(incl, off);
        if (lane >= off) incl += y;
    }
    if (lane == 63) wsum[wid] = incl;
    __syncthreads();
    int wb = 0;
    #pragma unroll
    for (int w = 0; w < 4; w++) if (w < wid) wb += wsum[w];
    int excl = wb + incl - tsum;
    a[t * 4] = excl; a[t * 4 + 1] = excl + c0;
    a[t * 4 + 2] = excl + c0 + c1; a[t * 4 + 3] = excl + c0 + c1 + c2;
    __syncthreads();
}

// pass B: block per (super-bucket, support). Counts local rows, derives rp,
// then places packets into the bucket's private pk window (single-writer lines).
__global__ __launch_bounds__(256) void fill_bucket(const int2* __restrict__ stage,
        const int* __restrict__ offTab, const int* __restrict__ lenTab,
        const int* __restrict__ bbase, int* __restrict__ rp, int2* __restrict__ pk,
        int NSB, int nchunks, int N, int E) {
    __shared__ int lh[SBROWS];
    __shared__ int wsum[4];
    int b = blockIdx.x, s = blockIdx.y, t = threadIdx.x;
    int rowbase = b << SBSHIFT;
    int nrows = N - rowbase; if (nrows > SBROWS) nrows = SBROWS;
    #pragma unroll
    for (int k = 0; k < 4; k++) lh[t + k * 256] = 0;
    __syncthreads();
    size_t sb = (size_t)s * E;
    int wid = t >> 6, lane = t & 63;
    for (int c = wid; c < nchunks; c += 4) {
        size_t tb = ((size_t)s * nchunks + c) * NSB + b;
        int off = offTab[tb], len = lenTab[tb];
        const int2* seg = stage + sb + (size_t)c * CH + off;
        for (int i = lane; i < len; i += 64)
            atomicAdd(&lh[((uint)seg[i].x) >> 20], 1);
    }
    __syncthreads();
    block_scan1024(lh, t, wsum);
    int bb = bbase[s * NSB + b];
    #pragma unroll
    for (int k = 0; k < 4; k++) {
        int i = t * 4 + k;
        int curv = lh[i] + bb;
        lh[i] = curv;
        if (i < nrows) rp[(size_t)s * (N + 1) + rowbase + i] = curv;
    }
    if (b == 0 && t == 0) rp[(size_t)s * (N + 1) + N] = E;
    __syncthreads();
    for (int c = wid; c < nchunks; c += 4) {
        size_t tb = ((size_t)s * nchunks + c) * NSB + b;
        int off = offTab[tb], len = lenTab[tb];
        const int2* seg = stage + sb + (size_t)c * CH + off;
        for (int i = lane; i < len; i += 64) {
            int2 u = seg[i];
            int lr = ((uint)u.x) >> 20;
            int pos = atomicAdd(&lh[lr], 1);
            pk[sb + pos] = make_int2(u.x & 0xFFFFF, u.y);
        }
    }
}

// ---------------- fused SpMM kernels ----------------

__global__ __launch_bounds__(256) void spmm_bp2(const int* __restrict__ rpA,
        const int2* __restrict__ pkA, const int* __restrict__ rpB,
        const int2* __restrict__ pkB, const uint* __restrict__ Xb,
        uint* __restrict__ outb, int N) {
    int gt = blockIdx.x * 256 + threadIdx.x;
    int row = gt >> 6, lane = gt & 63;
    if (row >= N) return;
    float sax = 0.f, say = 0.f, qax = 0.f, qay = 0.f;
    float sbx = 0.f, sby = 0.f, qbx = 0.f, qby = 0.f;
    {
        int e = rpA[row], end = rpA[row + 1];
        for (; e + 2 <= end; e += 2) {
            int2 c0 = ldnt(&pkA[e]); int2 c1 = ldnt(&pkA[e + 1]);
            uint u0 = Xb[(c0.x << 6) + lane];
            uint u1 = Xb[(c1.x << 6) + lane];
            float v0 = __int_as_float(c0.y), v1 = __int_as_float(c1.y);
            float x0 = bfl(u0), y0 = bfh(u0), x1 = bfl(u1), y1 = bfh(u1);
            sax = fmaf(v0, x0, sax); say = fmaf(v0, y0, say);
            qax = fmaf(v0 * x0, x0, qax); qay = fmaf(v0 * y0, y0, qay);
            sax = fmaf(v1, x1, sax); say = fmaf(v1, y1, say);
            qax = fmaf(v1 * x1, x1, qax); qay = fmaf(v1 * y1, y1, qay);
        }
        if (e < end) {
            int2 c0 = ldnt(&pkA[e]);
            uint u0 = Xb[(c0.x << 6) + lane];
            float v0 = __int_as_float(c0.y);
            float x0 = bfl(u0), y0 = bfh(u0);
            sax = fmaf(v0, x0, sax); say = fmaf(v0, y0, say);
            qax = fmaf(v0 * x0, x0, qax); qay = fmaf(v0 * y0, y0, qay);
        }
    }
    {
        int e = rpB[row], end = rpB[row + 1];
        for (; e + 2 <= end; e += 2) {
            int2 c0 = ldnt(&pkB[e]); int2 c1 = ldnt(&pkB[e + 1]);
            uint u0 = Xb[(c0.x << 6) + lane];
            uint u1 = Xb[(c1.x << 6) + lane];
            float v0 = __int_as_float(c0.y), v1 = __int_as_float(c1.y);
            float x0 = bfl(u0), y0 = bfh(u0), x1 = bfl(u1), y1 = bfh(u1);
            sbx = fmaf(v0, x0, sbx); sby = fmaf(v0, y0, sby);
            qbx = fmaf(v0 * x0, x0, qbx); qby = fmaf(v0 * y0, y0, qby);
            sbx = fmaf(v1, x1, sbx); sby = fmaf(v1, y1, sby);
            qbx = fmaf(v1 * x1, x1, qbx); qby = fmaf(v1 * y1, y1, qby);
        }
        if (e < end) {
            int2 c0 = ldnt(&pkB[e]);
            uint u0 = Xb[(c0.x << 6) + lane];
            float v0 = __int_as_float(c0.y);
            float x0 = bfl(u0), y0 = bfh(u0);
            sbx = fmaf(v0, x0, sbx); sby = fmaf(v0, y0, sby);
            qbx = fmaf(v0 * x0, x0, qbx); qby = fmaf(v0 * y0, y0, qby);
        }
    }
    float tx = 0.5f * ((sax * sax - qax) - (sbx * sbx - qbx));
    float ty = 0.5f * ((say * say - qay) - (sby * sby - qby));
    outb[((size_t)row << 6) + lane] = packbf2(tx, ty);
}

__global__ __launch_bounds__(256) void spmm_out(const int* __restrict__ rp0,
        const int2* __restrict__ pk0, const int* __restrict__ rp5,
        const int2* __restrict__ pk5, const int* __restrict__ rp6,
        const int2* __restrict__ pk6, const uint* __restrict__ Pb,
        const uint* __restrict__ t1b, const uint* __restrict__ t2b,
        float* __restrict__ out, int N) {
    int gt = blockIdx.x * 256 + threadIdx.x;
    int row = gt >> 6, lane = gt & 63;
    if (row >= N) return;
    float a0x = 0.f, a0y = 0.f, a5x = 0.f, a5y = 0.f, a6x = 0.f, a6y = 0.f;
    {
        int e = rp0[row], end = rp0[row + 1];
        for (; e + 2 <= end; e += 2) {
            int2 c0 = ldnt(&pk0[e]); int2 c1 = ldnt(&pk0[e + 1]);
            uint u0 = Pb[(c0.x << 6) + lane];
            uint u1 = Pb[(c1.x << 6) + lane];
            float v0 = __int_as_float(c0.y), v1 = __int_as_float(c1.y);
            a0x = fmaf(v0, bfl(u0), a0x); a0y = fmaf(v0, bfh(u0), a0y);
            a0x = fmaf(v1, bfl(u1), a0x); a0y = fmaf(v1, bfh(u1), a0y);
        }
        if (e < end) {
            int2 c0 = ldnt(&pk0[e]);
            uint u0 = Pb[(c0.x << 6) + lane];
            float v0 = __int_as_float(c0.y);
            a0x = fmaf(v0, bfl(u0), a0x); a0y = fmaf(v0, bfh(u0), a0y);
        }
    }
    {
        int e = rp5[row], end = rp5[row + 1];
        for (; e + 2 <= end; e += 2) {
            int2 c0 = ldnt(&pk5[e]); int2 c1 = ldnt(&pk5[e + 1]);
            uint u0 = t1b[(c0.x << 6) + lane];
            uint u1 = t1b[(c1.x << 6) + lane];
            float v0 = __int_as_float(c0.y), v1 = __int_as_float(c1.y);
            a5x = fmaf(v0, bfl(u0), a5x); a5y = fmaf(v0, bfh(u0), a5y);
            a5x = fmaf(v1, bfl(u1), a5x); a5y = fmaf(v1, bfh(u1), a5y);
        }
        if (e < end) {
            int2 c0 = ldnt(&pk5[e]);
            uint u0 = t1b[(c0.x << 6) + lane];
            float v0 = __int_as_float(c0.y);
            a5x = fmaf(v0, bfl(u0), a5x); a5y = fmaf(v0, bfh(u0), a5y);
        }
    }
    {
        int e = rp6[row], end = rp6[row + 1];
        for (; e + 2 <= end; e += 2) {
            int2 c0 = ldnt(&pk6[e]); int2 c1 = ldnt(&pk6[e + 1]);
            uint u0 = t2b[(c0.x << 6) + lane];
            uint u1 = t2b[(c1.x << 6) + lane];
            float v0 = __int_as_float(c0.y), v1 = __int_as_float(c1.y);
            a6x = fmaf(v0, bfl(u0), a6x); a6y = fmaf(v0, bfh(u0), a6y);
            a6x = fmaf(v1, bfl(u1), a6x); a6y = fmaf(v1, bfh(u1), a6y);
        }
        if (e < end) {
            int2 c0 = ldnt(&pk6[e]);
            uint u0 = t2b[(c0.x << 6) + lane];
            float v0 = __int_as_float(c0.y);
            a6x = fmaf(v0, bfl(u0), a6x); a6y = fmaf(v0, bfh(u0), a6y);
        }
    }
    float rx = fmaxf(0.5f * a0x + 0.25f * a5x + 0.25f * a6x, 0.f);
    float ry = fmaxf(0.5f * a0y + 0.25f * a5y + 0.25f * a6y, 0.f);
    *(float2*)(out + ((size_t)row << 7) + (lane << 1)) = make_float2(rx, ry);
}

// ---------------- launch ----------------

extern "C" void kernel_launch(void* const* d_in, const int* in_sizes, int n_in,
                              void* d_out, int out_size, void* d_ws, size_t ws_size,
                              hipStream_t stream) {
    (void)n_in; (void)out_size; (void)ws_size;
    const float* x   = (const float*)d_in[0];
    const float* Wa  = (const float*)d_in[1];
    const float* Wb  = (const float*)d_in[2];
    const float* w1  = (const float*)d_in[4];
    const float* b1  = (const float*)d_in[5];
    const float* w2  = (const float*)d_in[6];
    const int* rows  = (const int*)d_in[7];
    const int* cols  = (const int*)d_in[8];
    const float* vals = (const float*)d_in[9];
    float* out = (float*)d_out;

    const int N = in_sizes[0] / 256;
    const int E = in_sizes[7] / 7;
    const int NSB = (N + SBROWS - 1) >> SBSHIFT;
    const int nchunks = (E + CH - 1) / CH;

    // layout: Pb|t1b|t2b | pk (4E int2) | region{stage 4E int2 / AB N*256 f32} | rp | tables
    uint* Pb  = (uint*)d_ws;
    uint* t1b = Pb + (size_t)N * 64;
    uint* t2b = t1b + (size_t)N * 64;
    int2* pk  = (int2*)(t2b + (size_t)N * 64);
    size_t regionFloats = (size_t)N * 256;
    if ((size_t)8 * E > regionFloats) regionFloats = (size_t)8 * E;
    int2* stage = pk + (size_t)4 * E;
    float* AB   = (float*)stage;
    int* rp     = (int*)((float*)stage + regionFloats);
    int* offTab = rp + 4 * (size_t)(N + 1);
    int* lenTab = offTab + (size_t)4 * nchunks * NSB;
    int* bbase  = lenTab + (size_t)4 * nchunks * NSB;

    dim3 b256(256);
    int sgrid = (N + 3) / 4;

    dim3 ggrid((N + BM - 1) / BM, 2);
    gemm_kernel<<<ggrid, b256, 0, stream>>>(x, Wa, Wb, AB, N);
    attn_kernel<<<sgrid, b256, 0, stream>>>(AB, w1, b1, w2, Pb, N);

    auto build = [&](int4 map, int nsup) {
        fill_chunk<<<dim3(nchunks, nsup), b256, 0, stream>>>(rows, cols, vals, map,
                                                             stage, offTab, lenTab, NSB, nchunks, E);
        bucket_scan<<<nsup, b256, 0, stream>>>(lenTab, bbase, NSB, nchunks);
        fill_bucket<<<dim3(NSB, nsup), b256, 0, stream>>>(stage, offTab, lenTab, bbase,
                                                          rp, pk, NSB, nchunks, N, E);
    };

    const int NP1 = N + 1;

    // group A: slots {1,3,2,4}
    build(make_int4(1, 3, 2, 4), 4);
    spmm_bp2<<<sgrid, b256, 0, stream>>>(rp + 0 * NP1, pk + 0 * (size_t)E,
                                         rp + 1 * NP1, pk + 1 * (size_t)E, Pb, t1b, N);
    spmm_bp2<<<sgrid, b256, 0, stream>>>(rp + 2 * NP1, pk + 2 * (size_t)E,
                                         rp + 3 * NP1, pk + 3 * (size_t)E, Pb, t2b, N);

    // group B: slots {0,5,6}
    build(make_int4(0, 5, 6, 6), 3);
    spmm_out<<<sgrid, b256, 0, stream>>>(rp + 0 * NP1, pk + 0 * (size_t)E,
                                         rp + 1 * NP1, pk + 1 * (size_t)E,
                                         rp + 2 * NP1, pk + 2 * (size_t)E,
                                         Pb, t1b, t2b, out, N);
}